// Round 1
// baseline (225.599 us; speedup 1.0000x reference)
//
#include <hip/hip_runtime.h>

#define HW 4096
#define NCH 256
#define DIM 128
#define NPROTO 512

typedef __attribute__((ext_vector_type(4))) float f32x4;
typedef __attribute__((ext_vector_type(8))) short s16x8;

__device__ __forceinline__ unsigned short f2bf(float f) {
  union { float f; unsigned u; } v; v.f = f;
  unsigned r = v.u + 0x7fffu + ((v.u >> 16) & 1u);
  return (unsigned short)(r >> 16);
}
__device__ __forceinline__ float bf2f(unsigned short h) {
  union { unsigned u; float f; } v; v.u = ((unsigned)h) << 16;
  return v.f;
}

// ---------------------------------------------------------------------------
// prep: p_norm2[512] and prototypes -> bf16 in chunked layout Pr[ch][n][32]
// (chunk ch covers d-range [32*ch, 32*ch+32), so attn's staging reads are
//  fully contiguous 32KB blocks)
// ---------------------------------------------------------------------------
__global__ __launch_bounds__(256) void prep_kernel(const float* __restrict__ P,
                                                   unsigned short* __restrict__ Pr,
                                                   float* __restrict__ pn2) {
  const int tid = threadIdx.x;
  const int n  = blockIdx.x * 64 + (tid >> 2);
  const int qt = tid & 3;
  const float* row = P + n * DIM + qt * 32;
  unsigned short* dst = Pr + ((size_t)qt * NPROTO + n) * 32;
  float ssq = 0.f;
#pragma unroll
  for (int u = 0; u < 8; ++u) {
    f32x4 v = *(const f32x4*)(row + 4 * u);
    ssq += v.x * v.x + v.y * v.y + v.z * v.z + v.w * v.w;
    dst[4 * u + 0] = f2bf(v.x);
    dst[4 * u + 1] = f2bf(v.y);
    dst[4 * u + 2] = f2bf(v.z);
    dst[4 * u + 3] = f2bf(v.w);
  }
  ssq += __shfl_xor(ssq, 1);
  ssq += __shfl_xor(ssq, 2);
  if (qt == 0) pn2[n] = ssq;
}

// ---------------------------------------------------------------------------
// proj: q[t][d] = sum_c x[n,c,h,w] * W[d,c] + b[d], output bf16 [65536][128]
// Block: 512 thr (8 waves), tile 128 pixels x 128 d, K-loop over 256 ch.
// ---------------------------------------------------------------------------
__global__ __launch_bounds__(512) void proj_kernel(const float* __restrict__ x,
                                                   const float* __restrict__ Wm,
                                                   const float* __restrict__ bias,
                                                   unsigned short* __restrict__ qbf) {
  __shared__ __align__(16) unsigned short x_s[128 * 72];  // [pix][c] pad 64->72
  __shared__ __align__(16) unsigned short w_s[128 * 72];  // [d][c]   pad 64->72
  const int tid  = threadIdx.x;
  const int p0   = blockIdx.x * 128;
  const int nimg = p0 >> 12;
  const int hw0  = p0 & 4095;
  const float* xbase = x + (size_t)nimg * NCH * HW + hw0;
  const int wave = tid >> 6, lane = tid & 63;
  const int l15 = lane & 15, l4 = lane >> 4;

  f32x4 acc[8];
#pragma unroll
  for (int j = 0; j < 8; ++j)
#pragma unroll
    for (int r = 0; r < 4; ++r) acc[j][r] = 0.f;

  for (int c0 = 0; c0 < NCH; c0 += 64) {
    {
      const int f = tid & 31, cl = tid >> 5;  // f: float4 over 128 pix, cl: 0..15
#pragma unroll
      for (int r = 0; r < 4; ++r) {
        const int cc = cl + 16 * r;           // local c 0..63
        f32x4 v = *(const f32x4*)(xbase + (size_t)(c0 + cc) * HW + 4 * f);
        x_s[(4 * f + 0) * 72 + cc] = f2bf(v.x);
        x_s[(4 * f + 1) * 72 + cc] = f2bf(v.y);
        x_s[(4 * f + 2) * 72 + cc] = f2bf(v.z);
        x_s[(4 * f + 3) * 72 + cc] = f2bf(v.w);
      }
      const int f2 = tid & 15, dl = tid >> 4; // f2: float4 over 64 c, dl: 0..31
#pragma unroll
      for (int r = 0; r < 4; ++r) {
        const int d = dl + 32 * r;
        f32x4 v = *(const f32x4*)(Wm + d * NCH + c0 + 4 * f2);
        unsigned short* w = &w_s[d * 72 + 4 * f2];
        w[0] = f2bf(v.x); w[1] = f2bf(v.y); w[2] = f2bf(v.z); w[3] = f2bf(v.w);
      }
    }
    __syncthreads();
#pragma unroll
    for (int kc = 0; kc < 64; kc += 32) {
      s16x8 a = *(const s16x8*)&x_s[(16 * wave + l15) * 72 + kc + 8 * l4];
#pragma unroll
      for (int j = 0; j < 8; ++j) {
        s16x8 b = *(const s16x8*)&w_s[(16 * j + l15) * 72 + kc + 8 * l4];
        acc[j] = __builtin_amdgcn_mfma_f32_16x16x32_bf16(a, b, acc[j], 0, 0, 0);
      }
    }
    __syncthreads();
  }
  // epilogue: C/D layout col=lane&15 (=d within tile), row=(lane>>4)*4+reg (=pix)
  const int mb = 16 * wave + 4 * l4;
#pragma unroll
  for (int j = 0; j < 8; ++j) {
    const int d = 16 * j + l15;
    const float bv = bias[d];
#pragma unroll
    for (int r = 0; r < 4; ++r)
      qbf[(size_t)(p0 + mb + r) * DIM + d] = f2bf(acc[j][r] + bv);
  }
}

// ---------------------------------------------------------------------------
// attn: S = q . P^T, logits = g*(2S - pnorm2), softmax over 512, write
// out[n,k,h,w]. Block: 512 thr (8 waves), tile 64 pixels x 512 protos.
// Wave w owns proto range [64w, 64w+64). Output goes through an LDS
// transpose so global stores are coalesced float4 along pixels.
// ---------------------------------------------------------------------------
__global__ __launch_bounds__(512) void attn_kernel(const unsigned short* __restrict__ qbf,
                                                   const unsigned short* __restrict__ Pr,
                                                   const float* __restrict__ pn2,
                                                   const float* __restrict__ gptr,
                                                   float* __restrict__ out) {
  __shared__ __align__(16) char smem[58368];
  unsigned short* q_s = (unsigned short*)smem;            // [64][136] bf16
  unsigned short* P_s = (unsigned short*)(smem + 17408);  // [512][40] bf16
  unsigned short* w_s = (unsigned short*)smem;            // [256][72] bf16 (phase 2)
  float* red  = (float*)(smem + 36864);                   // [8][64]
  float* rmx  = (float*)(smem + 36864 + 2048);            // [64]
  float* rinv = (float*)(smem + 36864 + 2048 + 256);      // [64]

  const int tid  = threadIdx.x;
  const int p0   = blockIdx.x * 64;
  const int nimg = p0 >> 12;
  const int hw0  = p0 & 4095;
  const int wave = tid >> 6, lane = tid & 63;
  const int l15 = lane & 15, l4 = lane >> 4;
  const float g = fabsf(gptr[0]);

  {  // stage q tile [64][128] bf16 -> LDS
    const int r = tid >> 3, c8 = tid & 7;
#pragma unroll
    for (int it = 0; it < 2; ++it) {
      const int col = c8 + 8 * it;  // unit: 8 bf16
      s16x8 v = *(const s16x8*)(qbf + (size_t)(p0 + r) * DIM + 8 * col);
      *(s16x8*)&q_s[r * 136 + 8 * col] = v;
    }
  }

  f32x4 acc[4][4];
#pragma unroll
  for (int i = 0; i < 4; ++i)
#pragma unroll
    for (int j = 0; j < 4; ++j)
#pragma unroll
      for (int r = 0; r < 4; ++r) acc[i][j][r] = 0.f;

  for (int ch = 0; ch < 4; ++ch) {
    if (ch) __syncthreads();  // previous chunk's readers done before restage
    {
      const unsigned short* src = Pr + ((size_t)ch * NPROTO + tid) * 32;
      unsigned short* dst = &P_s[tid * 40];
#pragma unroll
      for (int u = 0; u < 4; ++u)
        *(s16x8*)(dst + 8 * u) = *(const s16x8*)(src + 8 * u);
    }
    __syncthreads();
    const int dk = ch * 32;
    s16x8 afr[4];
#pragma unroll
    for (int i = 0; i < 4; ++i)
      afr[i] = *(const s16x8*)&q_s[(16 * i + l15) * 136 + dk + 8 * l4];
#pragma unroll
    for (int j = 0; j < 4; ++j) {
      s16x8 bfr = *(const s16x8*)&P_s[(64 * wave + 16 * j + l15) * 40 + 8 * l4];
#pragma unroll
      for (int i = 0; i < 4; ++i)
        acc[i][j] = __builtin_amdgcn_mfma_f32_16x16x32_bf16(afr[i], bfr, acc[i][j], 0, 0, 0);
    }
  }
  __syncthreads();  // all MFMA LDS reads done before epilogue reuses smem

  // logits + row max.  lane holds rows m = 16i + 4*l4 + r, cols n = 64w+16j+l15
  float pnv[4];
#pragma unroll
  for (int j = 0; j < 4; ++j) pnv[j] = pn2[64 * wave + 16 * j + l15];

#pragma unroll
  for (int i = 0; i < 4; ++i)
#pragma unroll
    for (int r = 0; r < 4; ++r) {
      float m = -1e30f;
#pragma unroll
      for (int j = 0; j < 4; ++j) {
        float lv = g * (2.f * acc[i][j][r] - pnv[j]);
        acc[i][j][r] = lv;
        m = fmaxf(m, lv);
      }
#pragma unroll
      for (int s = 1; s < 16; s <<= 1) m = fmaxf(m, __shfl_xor(m, s));
      if (l15 == 0) red[wave * 64 + 16 * i + 4 * l4 + r] = m;
    }
  __syncthreads();
  if (tid < 64) {
    float M = red[tid];
#pragma unroll
    for (int w = 1; w < 8; ++w) M = fmaxf(M, red[w * 64 + tid]);
    rmx[tid] = M;
  }
  __syncthreads();

  // exp + row sum
#pragma unroll
  for (int i = 0; i < 4; ++i)
#pragma unroll
    for (int r = 0; r < 4; ++r) {
      const float M = rmx[16 * i + 4 * l4 + r];
      float s = 0.f;
#pragma unroll
      for (int j = 0; j < 4; ++j) {
        float e = __expf(acc[i][j][r] - M);
        acc[i][j][r] = e;
        s += e;
      }
#pragma unroll
      for (int t = 1; t < 16; t <<= 1) s += __shfl_xor(s, t);
      if (l15 == 0) red[wave * 64 + 16 * i + 4 * l4 + r] = s;
    }
  __syncthreads();
  if (tid < 64) {
    float S = 0.f;
#pragma unroll
    for (int w = 0; w < 8; ++w) S += red[w * 64 + tid];
    rinv[tid] = 1.f / S;
  }
  __syncthreads();

  float inv[4][4];
#pragma unroll
  for (int i = 0; i < 4; ++i)
#pragma unroll
    for (int r = 0; r < 4; ++r) inv[i][r] = rinv[16 * i + 4 * l4 + r];

  const size_t outbase = (size_t)nimg * NPROTO * HW + hw0;
#pragma unroll
  for (int half = 0; half < 2; ++half) {
    if ((wave >> 2) == half) {  // waves owning this n-half write w_s[k_local][pix]
      const int wl = wave & 3;
#pragma unroll
      for (int i = 0; i < 4; ++i)
#pragma unroll
        for (int j = 0; j < 4; ++j) {
          const int nl = 64 * wl + 16 * j + l15;
#pragma unroll
          for (int r = 0; r < 4; ++r)
            w_s[nl * 72 + 16 * i + 4 * l4 + r] = f2bf(acc[i][j][r] * inv[i][r]);
        }
    }
    __syncthreads();
    {  // coalesced copy-out: 256 k-planes x 64 pixels, float4 per lane
      const int f4 = tid & 15, kl = tid >> 4;
#pragma unroll
      for (int it = 0; it < 8; ++it) {
        const int kloc = kl + 32 * it;
        const unsigned short* src = &w_s[kloc * 72 + 4 * f4];
        f32x4 o;
        o.x = bf2f(src[0]); o.y = bf2f(src[1]);
        o.z = bf2f(src[2]); o.w = bf2f(src[3]);
        *(f32x4*)(out + outbase + (size_t)(half * 256 + kloc) * HW + 4 * f4) = o;
      }
    }
    __syncthreads();  // half-0 reads done before half-1 overwrites w_s
  }
}

extern "C" void kernel_launch(void* const* d_in, const int* in_sizes, int n_in,
                              void* d_out, int out_size, void* d_ws, size_t ws_size,
                              hipStream_t stream) {
  const float* x     = (const float*)d_in[0];
  const float* Wm    = (const float*)d_in[1];
  const float* bias  = (const float*)d_in[2];
  const float* prot  = (const float*)d_in[3];
  const float* gamma = (const float*)d_in[4];
  float* out = (float*)d_out;

  // workspace layout: q bf16 (16 MiB) | P bf16 chunked (128 KiB) | pn2 (2 KiB)
  unsigned short* q_ws  = (unsigned short*)d_ws;
  unsigned short* P_ws  = (unsigned short*)((char*)d_ws + 16777216);
  float*          pn2_w = (float*)((char*)d_ws + 16777216 + 131072);

  prep_kernel<<<8, 256, 0, stream>>>(prot, P_ws, pn2_w);
  proj_kernel<<<512, 512, 0, stream>>>(x, Wm, bias, q_ws);
  attn_kernel<<<1024, 512, 0, stream>>>(q_ws, P_ws, pn2_w, gamma, out);
}